// Round 7
// baseline (700.480 us; speedup 1.0000x reference)
//
#include <hip/hip_runtime.h>

typedef unsigned short u16;
typedef u16 u16x8 __attribute__((ext_vector_type(8)));
typedef u16 u16x4 __attribute__((ext_vector_type(4)));
typedef float f32x4v __attribute__((ext_vector_type(4)));
typedef __bf16 bf16x8 __attribute__((ext_vector_type(8)));

// ---------- helpers ----------
__device__ __forceinline__ u16 f2bf(float f) {
  unsigned u = __builtin_bit_cast(unsigned, f);
  u += 0x7fffu + ((u >> 16) & 1u);  // round-to-nearest-even
  return (u16)(u >> 16);
}

// ---------- fp32 -> bf16 conversion ----------
__global__ __launch_bounds__(256) void cvt_f32_bf16(const float* __restrict__ in,
                                                    u16* __restrict__ out, long n) {
  long i0 = ((long)blockIdx.x * 256 + threadIdx.x) * 8;
  long stride = (long)gridDim.x * 256 * 8;
  for (long i = i0; i < n; i += stride) {
    float4 a = *(const float4*)(in + i);
    float4 b = *(const float4*)(in + i + 4);
    u16x8 o;
    o[0] = f2bf(a.x); o[1] = f2bf(a.y); o[2] = f2bf(a.z); o[3] = f2bf(a.w);
    o[4] = f2bf(b.x); o[5] = f2bf(b.y); o[6] = f2bf(b.z); o[7] = f2bf(b.w);
    *(u16x8*)(out + i) = o;
  }
}

// ---------- 128x128 GEMM, A[M,K] x B[N,K]^T, 4 waves, 3-slot LDS ring (48 KiB) ----------
// Goal: 3 blocks/CU (12 waves) of TLP + counted-vmcnt pipeline.
// LDS 48 KiB: A slot s (s=H%3) at s*4096 u16 ([128 rows][32 k] bf16, swizzled);
//             B slots at u16 12288 + s*4096.  Half H = 32 consecutive k.
// Swizzle: 16B chunk c of row r holds global chunk c ^ ((r>>1)&3) (involution).
// STAGING (m104-legal): every GLDS dest = uniform slot base + t*16B; thread t sources
// row t>>2 (and +64), global chunk (t&3)^((row>>1)&3).
// Phase H: { 8x ds_read_b128 (slot H%3) ; stage half H+2 -> slot (H+2)%3 ;
//            barrier ; lgkmcnt(0) ; setprio(1) ; 16 MFMA ; setprio(0) ; wait ; barrier }
// Slot safety: (H+2)%3 == (H-1)%3, last read in phase H-1; those ds_reads retired at
// phase H-1's lgkmcnt(0) (all waves) before its end barrier, and phase H's stage is
// issued after that barrier.
// vmcnt (FIFO-exact): end of phase H needs half H+1 landed. Loads newer than stage(H+1):
// only stage(H+2) (4 loads, issued this phase) -> vmcnt(4) if staged, else vmcnt(0);
// no wait when H+1==NH. Prologue stages halves 0,1 (8 loads), vmcnt(4) -> half 0 landed.
template <int EPI>
__global__ __launch_bounds__(256, 3) void gemm128(
    const u16* __restrict__ A, long lda, long bsA,
    const u16* __restrict__ B, long ldb, long bsB,
    void* __restrict__ Cv, long ldc, long bsC, int K,
    const int* __restrict__ maskp, float scale,
    const float* __restrict__ bias) {
  __shared__ u16 sm[24576];
  const int t = threadIdx.x;
  const int lane = t & 63;
  const int w = t >> 6;
  const int wr = w >> 1;   // 0..1 : 64-row group
  const int wc = w & 1;    // 0..1 : 64-col group

  const int bx = blockIdx.x;
  const int by = blockIdx.y;
  const int bz = blockIdx.z;

  const u16* Ab = A + (long)bz * bsA + (long)bx * 128 * lda;
  const u16* Bb = B + (long)bz * bsB + (long)by * 128 * ldb;

  // staging sources (dest is linear t*16B; source pre-swizzled)
  const int srow = t >> 2;                       // 0..63
  const int scw = ((t & 3) ^ ((srow >> 1) & 3)) * 8;
  const u16* gA  = Ab + (long)srow * lda + scw;  // rows 0..63
  const u16* gAh = gA + 64 * lda;                // rows 64..127 (same xor term)
  const u16* gB  = Bb + (long)srow * ldb + scw;
  const u16* gBh = gB + 64 * ldb;

#define GLDS(gptr, lidx)                                                        \
  __builtin_amdgcn_global_load_lds(                                             \
      (const __attribute__((address_space(1))) void*)(gptr),                    \
      (__attribute__((address_space(3))) void*)(sm + (lidx)), 16, 0, 0)

#define STAGE_AB(Hs)                                                            \
  do {                                                                          \
    const int slotb_ = ((Hs) % 3) * 4096;                                       \
    const long ko_ = (long)(Hs) * 32;                                           \
    GLDS(gA + ko_,  slotb_ + t * 8);                                            \
    GLDS(gAh + ko_, slotb_ + 2048 + t * 8);                                     \
    GLDS(gB + ko_,  12288 + slotb_ + t * 8);                                    \
    GLDS(gBh + ko_, 12288 + slotb_ + 2048 + t * 8);                             \
  } while (0)

  f32x4v acc[4][4];
#pragma unroll
  for (int i = 0; i < 4; ++i)
#pragma unroll
    for (int j = 0; j < 4; ++j) acc[i][j] = (f32x4v){0.f, 0.f, 0.f, 0.f};

  // ds_read fragment addressing ((r>>1)&3 is fr-invariant: fr steps rows by 16)
  const int rA0 = wr * 64 + (lane & 15);
  const int rB0 = wc * 64 + (lane & 15);
  const int aoffb = rA0 * 32 + (((lane >> 4) ^ ((rA0 >> 1) & 3)) * 8);
  const int boffb = 12288 + rB0 * 32 + (((lane >> 4) ^ ((rB0 >> 1) & 3)) * 8);

  const int NH = K >> 5;  // 32-k halves

  // prologue: halves 0,1 (8 loads); vmcnt(4) -> half 0 landed
  STAGE_AB(0);
  STAGE_AB(1);
  asm volatile("s_waitcnt vmcnt(4)" ::: "memory");
  __builtin_amdgcn_s_barrier();

  for (int H = 0; H < NH; ++H) {
    const int slotb = (H % 3) * 4096;
    bf16x8 af[4], bq[4];
#pragma unroll
    for (int fr = 0; fr < 4; ++fr) af[fr] = *(const bf16x8*)(sm + slotb + aoffb + fr * 512);
#pragma unroll
    for (int fc = 0; fc < 4; ++fc) bq[fc] = *(const bf16x8*)(sm + slotb + boffb + fc * 512);
    if (H + 2 < NH) STAGE_AB(H + 2);
    __builtin_amdgcn_s_barrier();
    asm volatile("s_waitcnt lgkmcnt(0)" ::: "memory");
    __builtin_amdgcn_s_setprio(1);
#pragma unroll
    for (int fr = 0; fr < 4; ++fr)
#pragma unroll
      for (int fc = 0; fc < 4; ++fc)
        acc[fr][fc] = __builtin_amdgcn_mfma_f32_16x16x32_bf16(af[fr], bq[fc], acc[fr][fc], 0, 0, 0);
    __builtin_amdgcn_s_setprio(0);
    if (H + 1 < NH) {
      if (H + 2 < NH)
        asm volatile("s_waitcnt vmcnt(4)" ::: "memory");
      else
        asm volatile("s_waitcnt vmcnt(0)" ::: "memory");
    }
    __builtin_amdgcn_s_barrier();
  }
#undef STAGE_AB
#undef GLDS

  // ---- epilogue: C/D layout col = lane&15, row = (lane>>4)*4 + reg ----
  const long row0 = (long)bx * 128 + wr * 64;
  const long col0 = (long)by * 128 + wc * 64;
  const int l4 = lane >> 4;
  const int cl = lane & 15;
  if constexpr (EPI == 0) {
    float* C = (float*)Cv + (long)bz * bsC;
    const int* mrow = maskp + (long)bz * 2048;
#pragma unroll
    for (int fc = 0; fc < 4; ++fc) {
      long col = col0 + fc * 16 + cl;
      int mk = mrow[col];
#pragma unroll
      for (int fr = 0; fr < 4; ++fr) {
        long row = row0 + fr * 16 + l4 * 4;
#pragma unroll
        for (int r = 0; r < 4; ++r) {
          float v = mk ? acc[fr][fc][r] * scale + 1e-13f : -1e-13f;
          C[(row + r) * ldc + col] = v;
        }
      }
    }
  } else if constexpr (EPI == 1) {
    u16* C = (u16*)Cv + (long)bz * bsC;
#pragma unroll
    for (int fc = 0; fc < 4; ++fc) {
      long col = col0 + fc * 16 + cl;
#pragma unroll
      for (int fr = 0; fr < 4; ++fr) {
        long row = row0 + fr * 16 + l4 * 4;
#pragma unroll
        for (int r = 0; r < 4; ++r) C[(row + r) * ldc + col] = f2bf(acc[fr][fc][r]);
      }
    }
  } else {
    float* C = (float*)Cv;
#pragma unroll
    for (int fc = 0; fc < 4; ++fc) {
      long col = col0 + fc * 16 + cl;
      float bj = bias[col];
#pragma unroll
      for (int fr = 0; fr < 4; ++fr) {
        long row = row0 + fr * 16 + l4 * 4;
#pragma unroll
        for (int r = 0; r < 4; ++r) C[(row + r) * ldc + col] = acc[fr][fc][r] + bj;
      }
    }
  }
}

// ---------- row softmax: read 2048 f32, write 2048 bf16 in-place ----------
__global__ __launch_bounds__(256) void softmax_rows(float* __restrict__ S) {
  const int t = threadIdx.x;
  const float* row = S + (long)blockIdx.x * 2048;
  float4 x0 = ((const float4*)row)[t];
  float4 x1 = ((const float4*)row)[256 + t];
  float m = fmaxf(fmaxf(fmaxf(x0.x, x0.y), fmaxf(x0.z, x0.w)),
                  fmaxf(fmaxf(x1.x, x1.y), fmaxf(x1.z, x1.w)));
#pragma unroll
  for (int off = 32; off; off >>= 1) m = fmaxf(m, __shfl_xor(m, off));
  __shared__ float red[8];
  if ((t & 63) == 0) red[t >> 6] = m;
  __syncthreads();
  m = fmaxf(fmaxf(red[0], red[1]), fmaxf(red[2], red[3]));
  float p[8];
  p[0] = __expf(x0.x - m); p[1] = __expf(x0.y - m);
  p[2] = __expf(x0.z - m); p[3] = __expf(x0.w - m);
  p[4] = __expf(x1.x - m); p[5] = __expf(x1.y - m);
  p[6] = __expf(x1.z - m); p[7] = __expf(x1.w - m);
  float s = ((p[0] + p[1]) + (p[2] + p[3])) + ((p[4] + p[5]) + (p[6] + p[7]));
#pragma unroll
  for (int off = 32; off; off >>= 1) s += __shfl_xor(s, off);
  if ((t & 63) == 0) red[4 + (t >> 6)] = s;
  __syncthreads();
  float inv = 1.0f / (red[4] + red[5] + red[6] + red[7]);
  u16* prow = (u16*)S + (long)blockIdx.x * 4096;
  u16x4 o0, o1;
  o0[0] = f2bf(p[0] * inv); o0[1] = f2bf(p[1] * inv);
  o0[2] = f2bf(p[2] * inv); o0[3] = f2bf(p[3] * inv);
  o1[0] = f2bf(p[4] * inv); o1[1] = f2bf(p[5] * inv);
  o1[2] = f2bf(p[6] * inv); o1[3] = f2bf(p[7] * inv);
  *(u16x4*)(prow + 4 * t) = o0;
  *(u16x4*)(prow + 1024 + 4 * t) = o1;
}

// ---------- launcher ----------
extern "C" void kernel_launch(void* const* d_in, const int* in_sizes, int n_in,
                              void* d_out, int out_size, void* d_ws, size_t ws_size,
                              hipStream_t stream) {
  const float* Q = (const float*)d_in[0];
  const float* K = (const float*)d_in[1];
  const float* V = (const float*)d_in[2];
  const int* mask = (const int*)d_in[3];
  const float* W = (const float*)d_in[4];
  const float* bias = (const float*)d_in[5];

  const long NQ = 16L * 2048 * 1024;
  u16* Qb = (u16*)d_ws;
  u16* Kb = Qb + NQ;
  u16* Vb = Kb + NQ;
  u16* Wb = Vb + NQ;
  float* S = (float*)(Wb + 1024L * 1024);  // [16][2048][2048] f32; P bf16 in-place
  u16* R = Qb;                             // alias: Qb dead after GEMM1

  cvt_f32_bf16<<<2048, 256, 0, stream>>>(Q, Qb, NQ);
  cvt_f32_bf16<<<2048, 256, 0, stream>>>(K, Kb, NQ);
  cvt_f32_bf16<<<2048, 256, 0, stream>>>(V, Vb, NQ);
  cvt_f32_bf16<<<512, 256, 0, stream>>>(W, Wb, 1024L * 1024);

  // S = QK^T * scale (+1e-13), masked cols -> -1e-13   [2048 x 2048 x 1024] x16
  gemm128<0><<<dim3(16, 16, 16), 256, 0, stream>>>(
      Qb, 1024, 2048L * 1024, Kb, 1024, 2048L * 1024,
      S, 2048, 2048L * 2048, 1024, mask, 0.03125f, nullptr);

  softmax_rows<<<32768, 256, 0, stream>>>(S);

  // R = P V^T   [2048 x 1024 x 2048] x16 ; P lda 4096 (bf16 inside f32 rows)
  gemm128<1><<<dim3(16, 8, 16), 256, 0, stream>>>(
      (const u16*)S, 4096, 2048L * 4096, Vb, 2048, 1024L * 2048,
      R, 1024, 2048L * 1024, 2048, nullptr, 1.f, nullptr);

  // out = R W^T + bias   [32768 x 1024 x 1024]
  gemm128<2><<<dim3(256, 8, 1), 256, 0, stream>>>(
      R, 1024, 0, Wb, 1024, 0,
      d_out, 1024, 0, 1024, nullptr, 1.f, bias);
}

// Round 8
// 617.341 us; speedup vs baseline: 1.1347x; 1.1347x over previous
//
#include <hip/hip_runtime.h>

typedef unsigned short u16;
typedef u16 u16x8 __attribute__((ext_vector_type(8)));
typedef u16 u16x4 __attribute__((ext_vector_type(4)));
typedef float f32x4v __attribute__((ext_vector_type(4)));
typedef __bf16 bf16x8 __attribute__((ext_vector_type(8)));

// ---------- helpers ----------
__device__ __forceinline__ u16 f2bf(float f) {
  unsigned u = __builtin_bit_cast(unsigned, f);
  u += 0x7fffu + ((u >> 16) & 1u);  // round-to-nearest-even
  return (u16)(u >> 16);
}
__device__ __forceinline__ float bf2f(u16 b) {
  return __builtin_bit_cast(float, (unsigned)b << 16);
}

// ---------- fp32 -> bf16 conversion ----------
__global__ __launch_bounds__(256) void cvt_f32_bf16(const float* __restrict__ in,
                                                    u16* __restrict__ out, long n) {
  long i0 = ((long)blockIdx.x * 256 + threadIdx.x) * 8;
  long stride = (long)gridDim.x * 256 * 8;
  for (long i = i0; i < n; i += stride) {
    float4 a = *(const float4*)(in + i);
    float4 b = *(const float4*)(in + i + 4);
    u16x8 o;
    o[0] = f2bf(a.x); o[1] = f2bf(a.y); o[2] = f2bf(a.z); o[3] = f2bf(a.w);
    o[4] = f2bf(b.x); o[5] = f2bf(b.y); o[6] = f2bf(b.z); o[7] = f2bf(b.w);
    *(u16x8*)(out + i) = o;
  }
}

// ---------- 128x128 GEMM, A[M,K] x B[N,K]^T, 4 waves, 3-slot LDS ring (48 KiB) ----------
// Core identical to R7 (verified): counted-vmcnt ring, m104-legal staging, swizzle.
// EPI 0: E = bf16(exp(acc*scale+1e-13)) or 1.0 (masked); per-row partial sums of the
//        wave's 64 cols -> aux[(bz*2048+row)*32 + by*2 + wc]  (deterministic, no atomics)
// EPI 1: C = bf16(acc * aux[bz*2048+row])   (aux = Linv)
// EPI 2: C = f32 acc + bias[col]
template <int EPI>
__global__ __launch_bounds__(256, 3) void gemm128(
    const u16* __restrict__ A, long lda, long bsA,
    const u16* __restrict__ B, long ldb, long bsB,
    void* __restrict__ Cv, long ldc, long bsC, int K,
    const int* __restrict__ maskp, float scale,
    const float* __restrict__ bias, float* __restrict__ aux) {
  __shared__ u16 sm[24576];
  const int t = threadIdx.x;
  const int lane = t & 63;
  const int w = t >> 6;
  const int wr = w >> 1;   // 0..1 : 64-row group
  const int wc = w & 1;    // 0..1 : 64-col group

  const int bx = blockIdx.x;
  const int by = blockIdx.y;
  const int bz = blockIdx.z;

  const u16* Ab = A + (long)bz * bsA + (long)bx * 128 * lda;
  const u16* Bb = B + (long)bz * bsB + (long)by * 128 * ldb;

  // staging sources (dest is linear t*16B; source pre-swizzled)
  const int srow = t >> 2;                       // 0..63
  const int scw = ((t & 3) ^ ((srow >> 1) & 3)) * 8;
  const u16* gA  = Ab + (long)srow * lda + scw;  // rows 0..63
  const u16* gAh = gA + 64 * lda;                // rows 64..127 (same xor term)
  const u16* gB  = Bb + (long)srow * ldb + scw;
  const u16* gBh = gB + 64 * ldb;

#define GLDS(gptr, lidx)                                                        \
  __builtin_amdgcn_global_load_lds(                                             \
      (const __attribute__((address_space(1))) void*)(gptr),                    \
      (__attribute__((address_space(3))) void*)(sm + (lidx)), 16, 0, 0)

#define STAGE_AB(Hs)                                                            \
  do {                                                                          \
    const int slotb_ = ((Hs) % 3) * 4096;                                       \
    const long ko_ = (long)(Hs) * 32;                                           \
    GLDS(gA + ko_,  slotb_ + t * 8);                                            \
    GLDS(gAh + ko_, slotb_ + 2048 + t * 8);                                     \
    GLDS(gB + ko_,  12288 + slotb_ + t * 8);                                    \
    GLDS(gBh + ko_, 12288 + slotb_ + 2048 + t * 8);                             \
  } while (0)

  f32x4v acc[4][4];
#pragma unroll
  for (int i = 0; i < 4; ++i)
#pragma unroll
    for (int j = 0; j < 4; ++j) acc[i][j] = (f32x4v){0.f, 0.f, 0.f, 0.f};

  const int rA0 = wr * 64 + (lane & 15);
  const int rB0 = wc * 64 + (lane & 15);
  const int aoffb = rA0 * 32 + (((lane >> 4) ^ ((rA0 >> 1) & 3)) * 8);
  const int boffb = 12288 + rB0 * 32 + (((lane >> 4) ^ ((rB0 >> 1) & 3)) * 8);

  const int NH = K >> 5;  // 32-k halves

  STAGE_AB(0);
  STAGE_AB(1);
  asm volatile("s_waitcnt vmcnt(4)" ::: "memory");
  __builtin_amdgcn_s_barrier();

  for (int H = 0; H < NH; ++H) {
    const int slotb = (H % 3) * 4096;
    bf16x8 af[4], bq[4];
#pragma unroll
    for (int fr = 0; fr < 4; ++fr) af[fr] = *(const bf16x8*)(sm + slotb + aoffb + fr * 512);
#pragma unroll
    for (int fc = 0; fc < 4; ++fc) bq[fc] = *(const bf16x8*)(sm + slotb + boffb + fc * 512);
    if (H + 2 < NH) STAGE_AB(H + 2);
    __builtin_amdgcn_s_barrier();
    asm volatile("s_waitcnt lgkmcnt(0)" ::: "memory");
    __builtin_amdgcn_s_setprio(1);
#pragma unroll
    for (int fr = 0; fr < 4; ++fr)
#pragma unroll
      for (int fc = 0; fc < 4; ++fc)
        acc[fr][fc] = __builtin_amdgcn_mfma_f32_16x16x32_bf16(af[fr], bq[fc], acc[fr][fc], 0, 0, 0);
    __builtin_amdgcn_s_setprio(0);
    if (H + 1 < NH) {
      if (H + 2 < NH)
        asm volatile("s_waitcnt vmcnt(4)" ::: "memory");
      else
        asm volatile("s_waitcnt vmcnt(0)" ::: "memory");
    }
    __builtin_amdgcn_s_barrier();
  }
#undef STAGE_AB
#undef GLDS

  // ---- epilogue: C/D layout col = lane&15, row = (lane>>4)*4 + reg ----
  const long row0 = (long)bx * 128 + wr * 64;
  const long col0 = (long)by * 128 + wc * 64;
  const int l4 = lane >> 4;
  const int cl = lane & 15;
  if constexpr (EPI == 0) {
    u16* C = (u16*)Cv + (long)bz * bsC;
    const int* mrow = maskp + (long)bz * 2048;
    int mk4[4];
#pragma unroll
    for (int fc = 0; fc < 4; ++fc) mk4[fc] = mrow[col0 + fc * 16 + cl];
#pragma unroll
    for (int fr = 0; fr < 4; ++fr) {
#pragma unroll
      for (int r = 0; r < 4; ++r) {
        long row = row0 + fr * 16 + l4 * 4 + r;
        float s = 0.f;
#pragma unroll
        for (int fc = 0; fc < 4; ++fc) {
          long col = col0 + fc * 16 + cl;
          float e = mk4[fc] ? __expf(acc[fr][fc][r] * scale + 1e-13f) : 1.0f;
          u16 eb = f2bf(e);
          C[row * ldc + col] = eb;
          s += bf2f(eb);  // sum the rounded value (consistent with E)
        }
        s += __shfl_xor(s, 1);
        s += __shfl_xor(s, 2);
        s += __shfl_xor(s, 4);
        s += __shfl_xor(s, 8);
        if (cl == 0) aux[((long)bz * 2048 + row) * 32 + by * 2 + wc] = s;
      }
    }
  } else if constexpr (EPI == 1) {
    u16* C = (u16*)Cv + (long)bz * bsC;
    const float* linv = aux + (long)bz * 2048;
#pragma unroll
    for (int fr = 0; fr < 4; ++fr) {
#pragma unroll
      for (int r = 0; r < 4; ++r) {
        long row = row0 + fr * 16 + l4 * 4 + r;
        float li = linv[row];
#pragma unroll
        for (int fc = 0; fc < 4; ++fc) {
          long col = col0 + fc * 16 + cl;
          C[row * ldc + col] = f2bf(acc[fr][fc][r] * li);
        }
      }
    }
  } else {
    float* C = (float*)Cv;
#pragma unroll
    for (int fc = 0; fc < 4; ++fc) {
      long col = col0 + fc * 16 + cl;
      float bj = bias[col];
#pragma unroll
      for (int fr = 0; fr < 4; ++fr) {
        long row = row0 + fr * 16 + l4 * 4;
#pragma unroll
        for (int r = 0; r < 4; ++r) C[(row + r) * ldc + col] = acc[fr][fc][r] + bj;
      }
    }
  }
}

// ---------- per-row 1/sum of 32 partials ----------
__global__ __launch_bounds__(256) void rowsum_inv(const float* __restrict__ part,
                                                  float* __restrict__ linv) {
  int i = blockIdx.x * 256 + threadIdx.x;  // 0..32767
  const float4* p = (const float4*)(part + (long)i * 32);
  float s = 0.f;
#pragma unroll
  for (int j = 0; j < 8; ++j) {
    float4 v = p[j];
    s += (v.x + v.y) + (v.z + v.w);
  }
  linv[i] = 1.0f / s;
}

// ---------- launcher ----------
extern "C" void kernel_launch(void* const* d_in, const int* in_sizes, int n_in,
                              void* d_out, int out_size, void* d_ws, size_t ws_size,
                              hipStream_t stream) {
  const float* Q = (const float*)d_in[0];
  const float* K = (const float*)d_in[1];
  const float* V = (const float*)d_in[2];
  const int* mask = (const int*)d_in[3];
  const float* W = (const float*)d_in[4];
  const float* bias = (const float*)d_in[5];

  const long NQ = 16L * 2048 * 1024;       // 33,554,432
  u16* Qb = (u16*)d_ws;
  u16* Kb = Qb + NQ;
  u16* Vb = Kb + NQ;
  u16* Wb = Vb + NQ;                        // 1M u16
  u16* Eb = Wb + 1024L * 1024;              // [16][2048][2048] bf16 (134 MB)
  float* Part = (float*)(Eb + 16L * 2048 * 2048);  // [16*2048][32] f32 (4 MB)
  float* Linv = Part + 32768L * 32;         // [16*2048] f32
  u16* R = Qb;                              // alias: Qb dead after GEMM1

  cvt_f32_bf16<<<2048, 256, 0, stream>>>(Q, Qb, NQ);
  cvt_f32_bf16<<<2048, 256, 0, stream>>>(K, Kb, NQ);
  cvt_f32_bf16<<<2048, 256, 0, stream>>>(V, Vb, NQ);
  cvt_f32_bf16<<<512, 256, 0, stream>>>(W, Wb, 1024L * 1024);

  // E = exp(QK^T*scale+1e-13) (masked cols -> 1.0), bf16 + per-row partial sums
  gemm128<0><<<dim3(16, 16, 16), 256, 0, stream>>>(
      Qb, 1024, 2048L * 1024, Kb, 1024, 2048L * 1024,
      Eb, 2048, 2048L * 2048, 1024, mask, 0.03125f, nullptr, Part);

  rowsum_inv<<<128, 256, 0, stream>>>(Part, Linv);

  // R = (E V^T) * Linv[row], bf16
  gemm128<1><<<dim3(16, 8, 16), 256, 0, stream>>>(
      Eb, 2048, 2048L * 2048, Vb, 2048, 1024L * 2048,
      R, 1024, 2048L * 1024, 2048, nullptr, 1.f, nullptr, Linv);

  // out = R W^T + bias
  gemm128<2><<<dim3(256, 8, 1), 256, 0, stream>>>(
      R, 1024, 0, Wb, 1024, 0,
      d_out, 1024, 0, 1024, nullptr, 1.f, bias, nullptr);
}